// Round 6
// baseline (182.526 us; speedup 1.0000x reference)
//
#include <hip/hip_runtime.h>
#include <hip/hip_bf16.h>

// ---------------------------------------------------------------------------
// LogicLayer inference (size=1024, prev=1024, batch=16384)
//   out[s,n] = w0[s] + wA[s]*a + wB[s]*b + wAB[s]*a*b,  a = pA@prev, b = pB@prev
// Round 6: A-operand bypasses LDS entirely (direct global->VGPR b128 frags,
// L2-resident panels), B keeps the r4 staged+swizzled LDS path.
//   - LDS pipe work per tile: 24->8 ds_reads/wave + 32KB (not 64KB) stage
//   - 2 MFMA clusters (32 each) per BK=64 tile, ONE barrier + ONE vmcnt(0)
//     per tile; every waited load is >= 1 full tile old (~2800cy lead)
//   - A loads for tile T+1 issued after each cluster of tile T, pinned by
//     sched_barrier(0); compiler tracks their vmcnt deps automatically
// ---------------------------------------------------------------------------

typedef __attribute__((ext_vector_type(8))) short bf16x8;
typedef __attribute__((ext_vector_type(4))) float f32x4;

__device__ __forceinline__ void gload_lds16(const void* g, void* l) {
    __builtin_amdgcn_global_load_lds(
        (const __attribute__((address_space(1))) void*)g,
        (__attribute__((address_space(3))) void*)l, 16, 0, 0);
}

// ---------------- kernel 1: row softmax of WA/WB -> bf16 -------------------
__global__ __launch_bounds__(256) void softmax_rows_bf16(
    const float* __restrict__ WA, const float* __restrict__ WB,
    __hip_bfloat16* __restrict__ PA, __hip_bfloat16* __restrict__ PB,
    int rows, int cols)
{
    const int b = blockIdx.x;
    const float* W;
    __hip_bfloat16* P;
    if (b < rows) { W = WA + (size_t)b * cols;          P = PA + (size_t)b * cols; }
    else          { W = WB + (size_t)(b - rows) * cols; P = PB + (size_t)(b - rows) * cols; }

    const int t = threadIdx.x;
    const int wave = t >> 6, lane = t & 63;

    float4 v = *(const float4*)&W[t * 4];
    float mx = fmaxf(fmaxf(v.x, v.y), fmaxf(v.z, v.w));
    #pragma unroll
    for (int off = 32; off; off >>= 1) mx = fmaxf(mx, __shfl_xor(mx, off));

    __shared__ float redmax[4];
    __shared__ float redsum[4];
    if (lane == 0) redmax[wave] = mx;
    __syncthreads();
    mx = fmaxf(fmaxf(redmax[0], redmax[1]), fmaxf(redmax[2], redmax[3]));

    float e0 = __expf(v.x - mx), e1 = __expf(v.y - mx);
    float e2 = __expf(v.z - mx), e3 = __expf(v.w - mx);
    float s = e0 + e1 + e2 + e3;
    #pragma unroll
    for (int off = 32; off; off >>= 1) s += __shfl_xor(s, off);
    if (lane == 0) redsum[wave] = s;
    __syncthreads();
    s = redsum[0] + redsum[1] + redsum[2] + redsum[3];

    const float inv = 1.0f / s;
    __align__(8) __hip_bfloat16 o[4];
    o[0] = __float2bfloat16(e0 * inv);
    o[1] = __float2bfloat16(e1 * inv);
    o[2] = __float2bfloat16(e2 * inv);
    o[3] = __float2bfloat16(e3 * inv);
    *(uint2*)&P[t * 4] = *(const uint2*)o;
}

// ---------------- kernel 2: table softmax -> bilinear coeffs ----------------
__global__ void table_coef(const float* __restrict__ TW, float4* __restrict__ coef, int size)
{
    const int s = blockIdx.x * blockDim.x + threadIdx.x;
    if (s >= size) return;
    float p[16];
    float mx = -1e30f;
    #pragma unroll
    for (int g = 0; g < 16; ++g) { p[g] = TW[g * size + s]; mx = fmaxf(mx, p[g]); }
    float sum = 0.f;
    #pragma unroll
    for (int g = 0; g < 16; ++g) { p[g] = __expf(p[g] - mx); sum += p[g]; }
    const float inv = 1.0f / sum;
    #pragma unroll
    for (int g = 0; g < 16; ++g) p[g] *= inv;

    float w0  = p[8] + p[9] + p[10] + p[11] + p[12] + p[13] + p[14] + p[15];
    float wA  = p[2] + p[3] + p[6] + p[7] - p[8] - p[9] - p[12] - p[13];
    float wB  = p[4] + p[5] + p[6] + p[7] - p[8] - p[9] - p[10] - p[11];
    float wAB = p[1] - p[2] - p[4] - 2.f * p[6] - p[7]
              + p[8] + 2.f * p[9] + p[11] + p[13] - p[14];
    coef[s] = make_float4(w0, wA, wB, wAB);
}

// ---------------- kernel 3: prev (K x N f32) -> prevT (N x K bf16) ----------
__global__ __launch_bounds__(256) void transpose_bf16(
    const float* __restrict__ prev, __hip_bfloat16* __restrict__ prevT,
    int K, int N)
{
    __shared__ float ls[64][65];
    const int k0 = blockIdx.y * 64, n0 = blockIdx.x * 64;
    const int t = threadIdx.x;

    {
        const int kr = t >> 4, nc = (t & 15) * 4;
        #pragma unroll
        for (int i = 0; i < 4; ++i) {
            const int k = i * 16 + kr;
            float4 v = *(const float4*)&prev[(size_t)(k0 + k) * N + n0 + nc];
            ls[k][nc + 0] = v.x; ls[k][nc + 1] = v.y;
            ls[k][nc + 2] = v.z; ls[k][nc + 3] = v.w;
        }
    }
    __syncthreads();
    {
        const int n = t >> 2, kc = (t & 3) * 16;
        __align__(16) __hip_bfloat16 tmp[16];
        #pragma unroll
        for (int j = 0; j < 16; ++j) tmp[j] = __float2bfloat16(ls[kc + j][n]);
        __hip_bfloat16* dst = &prevT[(size_t)(n0 + n) * K + k0 + kc];
        *(uint4*)(dst + 0) = *(const uint4*)&tmp[0];
        *(uint4*)(dst + 8) = *(const uint4*)&tmp[8];
    }
}

// ---------------- kernel 4: dual GEMM, direct-global A ---------------------
// Block: out rows m0..m0+127 (both a and b GEMMs) x 256 cols, BK=64, 16 tiles.
// 8 waves 2(panel: wr=0 -> pA/a-acc, wr=1 -> pB/b-acc) x 4(N).
// B (prevT): LDS double-buffer 2x32KB @ {0, 32768}, r4's swizzle scheme.
// A (pA/pB): per-lane global b128 frags, issued 1 tile ahead, L1/L2-served.
constexpr int Kd = 1024;
constexpr int Nd = 16384;

__global__ __launch_bounds__(512, 2) void dual_gemm8(
    const __hip_bfloat16* __restrict__ pA,
    const __hip_bfloat16* __restrict__ pB,
    const __hip_bfloat16* __restrict__ prevT,
    const float4* __restrict__ coef,
    float* __restrict__ out)
{
    __shared__ __align__(16) char smem[131072];   // GEMM uses 64KB; epilogue all

    const int t_ = threadIdx.x;
    const int wave = t_ >> 6, lane = t_ & 63;
    const int wr = wave >> 2, wc = wave & 3;
    const int m0 = blockIdx.y * 128;
    const int n0 = blockIdx.x * 256;

    // fragment-read addressing for B (row stride 128B, chunk-XOR swizzle)
    const int fr  = lane & 15;
    const int kg  = lane >> 4;
    const int fsw = fr & 7;
    const int cc0 = (kg ^ fsw) * 16;              // ks0 chunk byte
    const int cc1 = ((4 + kg) ^ fsw) * 16;        // ks1 chunk byte
    const int boffs = (wc * 64 + fr) * 128;       // + j*2048 + buffer base

    // B staging (pre-swizzled global source), identical to r4
    const int sr  = lane >> 3;
    const int swz = ((lane & 7) ^ sr) * 8;
    const int r0  = wave * 16 + sr;
    const __hip_bfloat16* gB0 = prevT + (size_t)(n0 + r0) * Kd + swz;
    const __hip_bfloat16* gB1 = prevT + (size_t)(n0 + 128 + r0) * Kd + swz;

    // A direct-global fragment base: row = m0 + i*16 + fr, k = T*64 + ks*32 + kg*8
    const __hip_bfloat16* gPan = (wr ? pB : pA) + (size_t)(m0 + fr) * Kd + kg * 8;

    f32x4 acc[8][4] = {};
    bf16x8 aLo[8], aHi[8], b[8];

#define STG_B(T, BB) {                                                      \
    char* lb = smem + (BB) + wave * 2048;                                   \
    gload_lds16(gB0 + (T) * 64,           lb);                              \
    gload_lds16(gB0 + (T) * 64 + 8 * Kd,  lb + 1024);                       \
    gload_lds16(gB1 + (T) * 64,           lb + 16384);                      \
    gload_lds16(gB1 + (T) * 64 + 8 * Kd,  lb + 17408);                      \
    __builtin_amdgcn_sched_barrier(0); }

#define LD_ALO(T) { _Pragma("unroll") for (int i = 0; i < 4; ++i) {         \
    aLo[i*2]   = *(const bf16x8*)(gPan + (size_t)(i*16) * Kd + (T)*64);     \
    aLo[i*2+1] = *(const bf16x8*)(gPan + (size_t)(i*16) * Kd + (T)*64 + 32);} \
    __builtin_amdgcn_sched_barrier(0); }

#define LD_AHI(T) { _Pragma("unroll") for (int i = 0; i < 4; ++i) {         \
    aHi[i*2]   = *(const bf16x8*)(gPan + (size_t)(64+i*16) * Kd + (T)*64);  \
    aHi[i*2+1] = *(const bf16x8*)(gPan + (size_t)(64+i*16) * Kd + (T)*64 + 32);} \
    __builtin_amdgcn_sched_barrier(0); }

#define RD_B8(BB) { _Pragma("unroll") for (int j = 0; j < 4; ++j) {         \
    b[j*2]   = *(const bf16x8*)(smem + (BB) + boffs + j * 2048 + cc0);      \
    b[j*2+1] = *(const bf16x8*)(smem + (BB) + boffs + j * 2048 + cc1); } }

#define MM32(AR, I0)                                                        \
    asm volatile("s_waitcnt lgkmcnt(0)" ::: "memory");                      \
    __builtin_amdgcn_sched_barrier(0);                                      \
    __builtin_amdgcn_s_setprio(1);                                          \
    _Pragma("unroll") for (int i = 0; i < 4; ++i)                           \
    _Pragma("unroll") for (int j = 0; j < 4; ++j)                           \
    _Pragma("unroll") for (int ks = 0; ks < 2; ++ks)                        \
        acc[(I0)+i][j] = __builtin_amdgcn_mfma_f32_16x16x32_bf16(           \
            AR[i*2+ks], b[j*2+ks], acc[(I0)+i][j], 0, 0, 0);                \
    __builtin_amdgcn_s_setprio(0);

    // prologue: stage B(0), issue A(0); all confirmed at t=0's vmcnt(0)
    STG_B(0, 0)
    LD_ALO(0)
    LD_AHI(0)

    for (int t = 0; t < 15; ++t) {
        const int cb = (t & 1) << 15;             // current B buffer base
        const int nb = cb ^ 32768;
        asm volatile("s_waitcnt vmcnt(0)" ::: "memory");
        __builtin_amdgcn_s_barrier();
        RD_B8(cb)
        STG_B(t + 1, nb)                          // -> buffer last read at t-1
        MM32(aLo, 0)
        LD_ALO(t + 1)
        MM32(aHi, 4)
        LD_AHI(t + 1)
    }
    // tail tile 15 (odd -> buffer @32768), no prefetch
    asm volatile("s_waitcnt vmcnt(0)" ::: "memory");
    __builtin_amdgcn_s_barrier();
    RD_B8(32768)
    MM32(aLo, 0)
    MM32(aHi, 4)

#undef MM32
#undef RD_B8
#undef LD_ALO
#undef LD_AHI
#undef STG_B

    // ---- epilogue: exchange b-acc via LDS, fuse bilinear coefficients ----
    __syncthreads();
    if (wr == 1) {
        #pragma unroll
        for (int i = 0; i < 8; ++i) {
            #pragma unroll
            for (int j = 0; j < 4; ++j) {
                const int off = ((((wc * 8 + i) * 4 + j) * 64) + lane) * 16;
                *(f32x4*)(smem + off) = acc[i][j];
            }
        }
    }
    __syncthreads();
    if (wr == 0) {
        const int hi = lane >> 4;
        #pragma unroll
        for (int i = 0; i < 8; ++i) {
            float4 cc[4];
            #pragma unroll
            for (int r = 0; r < 4; ++r) cc[r] = coef[m0 + i * 16 + hi * 4 + r];
            #pragma unroll
            for (int j = 0; j < 4; ++j) {
                const f32x4 bb = *(const f32x4*)(smem + ((((wc * 8 + i) * 4 + j) * 64) + lane) * 16);
                const int n = n0 + wc * 64 + j * 16 + fr;
                #pragma unroll
                for (int r = 0; r < 4; ++r) {
                    const int m = m0 + i * 16 + hi * 4 + r;
                    const float aa = acc[i][j][r];
                    out[(size_t)m * Nd + n] = cc[r].x + cc[r].y * aa + cc[r].z * bb[r]
                                            + cc[r].w * (aa * bb[r]);
                }
            }
        }
    }
}

// ---------------------------------------------------------------------------
extern "C" void kernel_launch(void* const* d_in, const int* in_sizes, int n_in,
                              void* d_out, int out_size, void* d_ws, size_t ws_size,
                              hipStream_t stream)
{
    const float* prev = (const float*)d_in[0];   // (prev_size, batch)
    const float* WA   = (const float*)d_in[1];   // (size, prev_size)
    const float* WB   = (const float*)d_in[2];   // (size, prev_size)
    const float* TW   = (const float*)d_in[3];   // (16, size)
    float* out = (float*)d_out;                  // (size, batch)

    const int size      = in_sizes[3] / 16;          // 1024
    const int prev_size = in_sizes[1] / size;        // 1024
    const int batch     = in_sizes[0] / prev_size;   // 16384

    char* ws = (char*)d_ws;
    __hip_bfloat16* prevT = (__hip_bfloat16*)ws;     // 32MB
    size_t off = (size_t)batch * prev_size * sizeof(__hip_bfloat16);
    __hip_bfloat16* pA = (__hip_bfloat16*)(ws + off);
    off += (size_t)size * prev_size * sizeof(__hip_bfloat16);
    __hip_bfloat16* pB = (__hip_bfloat16*)(ws + off);
    off += (size_t)size * prev_size * sizeof(__hip_bfloat16);
    float4* coef = (float4*)(ws + off);

    softmax_rows_bf16<<<dim3(2 * size), dim3(256), 0, stream>>>(
        WA, WB, pA, pB, size, prev_size);
    table_coef<<<dim3((size + 255) / 256), dim3(256), 0, stream>>>(TW, coef, size);
    transpose_bf16<<<dim3(batch / 64, prev_size / 64), dim3(256), 0, stream>>>(
        prev, prevT, prev_size, batch);
    dual_gemm8<<<dim3(batch / 256, size / 128), dim3(512), 0, stream>>>(
        pA, pB, prevT, coef, out);
}

// Round 7
// 89.647 us; speedup vs baseline: 2.0360x; 2.0360x over previous
//
#include <hip/hip_runtime.h>
#include <hip/hip_bf16.h>

// ---------------------------------------------------------------------------
// LogicLayer inference (size=1024, prev=1024, batch=16384)
//   out[s,n] = w0[s] + wA[s]*a + wB[s]*b + wAB[s]*a*b,  a = pA@prev, b = pB@prev
// Round 7: r4's 4-phase skeleton with m201's wait discipline:
//   ONE vmcnt(2) per K-tile (at ph4), every waited stage >=1..3 phases old
//   (the 1-phase-old one is L2-hot pA/pB). Stage calendar for tile X:
//     gB0(X) @ X-2.ph4 | gB1(X) @ X-1.ph1 | gA0(X) @ X-1.ph2 | gA1(X) @ X-1.ph3
//   all confirmed by X-1.ph4's vmcnt(2)+barrier (per-wave stream hand-audited,
//   prologue+tail included; WAR: every stage >=2 barrier-pairs after the
//   region's last ds_read).
// ---------------------------------------------------------------------------

typedef __attribute__((ext_vector_type(8))) short bf16x8;
typedef __attribute__((ext_vector_type(4))) float f32x4;

__device__ __forceinline__ void gload_lds16(const void* g, void* l) {
    __builtin_amdgcn_global_load_lds(
        (const __attribute__((address_space(1))) void*)g,
        (__attribute__((address_space(3))) void*)l, 16, 0, 0);
}

// ---------------- kernel 1: row softmax of WA/WB -> bf16 -------------------
__global__ __launch_bounds__(256) void softmax_rows_bf16(
    const float* __restrict__ WA, const float* __restrict__ WB,
    __hip_bfloat16* __restrict__ PA, __hip_bfloat16* __restrict__ PB,
    int rows, int cols)
{
    const int b = blockIdx.x;
    const float* W;
    __hip_bfloat16* P;
    if (b < rows) { W = WA + (size_t)b * cols;          P = PA + (size_t)b * cols; }
    else          { W = WB + (size_t)(b - rows) * cols; P = PB + (size_t)(b - rows) * cols; }

    const int t = threadIdx.x;
    const int wave = t >> 6, lane = t & 63;

    float4 v = *(const float4*)&W[t * 4];
    float mx = fmaxf(fmaxf(v.x, v.y), fmaxf(v.z, v.w));
    #pragma unroll
    for (int off = 32; off; off >>= 1) mx = fmaxf(mx, __shfl_xor(mx, off));

    __shared__ float redmax[4];
    __shared__ float redsum[4];
    if (lane == 0) redmax[wave] = mx;
    __syncthreads();
    mx = fmaxf(fmaxf(redmax[0], redmax[1]), fmaxf(redmax[2], redmax[3]));

    float e0 = __expf(v.x - mx), e1 = __expf(v.y - mx);
    float e2 = __expf(v.z - mx), e3 = __expf(v.w - mx);
    float s = e0 + e1 + e2 + e3;
    #pragma unroll
    for (int off = 32; off; off >>= 1) s += __shfl_xor(s, off);
    if (lane == 0) redsum[wave] = s;
    __syncthreads();
    s = redsum[0] + redsum[1] + redsum[2] + redsum[3];

    const float inv = 1.0f / s;
    __align__(8) __hip_bfloat16 o[4];
    o[0] = __float2bfloat16(e0 * inv);
    o[1] = __float2bfloat16(e1 * inv);
    o[2] = __float2bfloat16(e2 * inv);
    o[3] = __float2bfloat16(e3 * inv);
    *(uint2*)&P[t * 4] = *(const uint2*)o;
}

// ---------------- kernel 2: table softmax -> bilinear coeffs ----------------
__global__ void table_coef(const float* __restrict__ TW, float4* __restrict__ coef, int size)
{
    const int s = blockIdx.x * blockDim.x + threadIdx.x;
    if (s >= size) return;
    float p[16];
    float mx = -1e30f;
    #pragma unroll
    for (int g = 0; g < 16; ++g) { p[g] = TW[g * size + s]; mx = fmaxf(mx, p[g]); }
    float sum = 0.f;
    #pragma unroll
    for (int g = 0; g < 16; ++g) { p[g] = __expf(p[g] - mx); sum += p[g]; }
    const float inv = 1.0f / sum;
    #pragma unroll
    for (int g = 0; g < 16; ++g) p[g] *= inv;

    float w0  = p[8] + p[9] + p[10] + p[11] + p[12] + p[13] + p[14] + p[15];
    float wA  = p[2] + p[3] + p[6] + p[7] - p[8] - p[9] - p[12] - p[13];
    float wB  = p[4] + p[5] + p[6] + p[7] - p[8] - p[9] - p[10] - p[11];
    float wAB = p[1] - p[2] - p[4] - 2.f * p[6] - p[7]
              + p[8] + 2.f * p[9] + p[11] + p[13] - p[14];
    coef[s] = make_float4(w0, wA, wB, wAB);
}

// ---------------- kernel 3: prev (K x N f32) -> prevT (N x K bf16) ----------
__global__ __launch_bounds__(256) void transpose_bf16(
    const float* __restrict__ prev, __hip_bfloat16* __restrict__ prevT,
    int K, int N)
{
    __shared__ float ls[64][65];
    const int k0 = blockIdx.y * 64, n0 = blockIdx.x * 64;
    const int t = threadIdx.x;

    {
        const int kr = t >> 4, nc = (t & 15) * 4;
        #pragma unroll
        for (int i = 0; i < 4; ++i) {
            const int k = i * 16 + kr;
            float4 v = *(const float4*)&prev[(size_t)(k0 + k) * N + n0 + nc];
            ls[k][nc + 0] = v.x; ls[k][nc + 1] = v.y;
            ls[k][nc + 2] = v.z; ls[k][nc + 3] = v.w;
        }
    }
    __syncthreads();
    {
        const int n = t >> 2, kc = (t & 3) * 16;
        __align__(16) __hip_bfloat16 tmp[16];
        #pragma unroll
        for (int j = 0; j < 16; ++j) tmp[j] = __float2bfloat16(ls[kc + j][n]);
        __hip_bfloat16* dst = &prevT[(size_t)(n0 + n) * K + k0 + kc];
        *(uint4*)(dst + 0) = *(const uint4*)&tmp[0];
        *(uint4*)(dst + 8) = *(const uint4*)&tmp[8];
    }
}

// ---------------- kernel 4: 4-phase dual GEMM, single-vmcnt discipline ------
// Block: 256 stacked A-rows (128 pA + 128 pB) x 256 cols, BK=64, 16 K-tiles.
// 8 waves 2(panel)x4(N), per-wave 128x64 out = 8x4 16x16 frags.
// LDS buffer (64KB): [ApA 16K @0][ApB @16384][B rows0-127 @32768][B rows128-255
// @49152]; 2 buffers. Rows 128B; chunk-XOR swizzle; same addressing as r4.
constexpr int Kd = 1024;
constexpr int Nd = 16384;

__global__ __launch_bounds__(512, 2) void dual_gemm8(
    const __hip_bfloat16* __restrict__ pA,
    const __hip_bfloat16* __restrict__ pB,
    const __hip_bfloat16* __restrict__ prevT,
    const float4* __restrict__ coef,
    float* __restrict__ out)
{
    __shared__ __align__(16) char smem[131072];

    const int t_ = threadIdx.x;
    const int wave = t_ >> 6, lane = t_ & 63;
    const int wr = wave >> 2, wc = wave & 3;      // wr: 0=pA panel, 1=pB panel
    const int m0 = blockIdx.y * 128;
    const int n0 = blockIdx.x * 256;

    // fragment-read addressing
    const int fr  = lane & 15;
    const int kg  = lane >> 4;
    const int fsw = fr & 7;
    const int c0 = (kg ^ fsw) * 16;               // kstep 0 chunk byte
    const int c1 = ((4 + kg) ^ fsw) * 16;         // kstep 1 chunk byte
    const int aoffs = (wr * 128 + fr) * 128;      // + i*2048 (+8192 for hi)
    const int boffs = 32768 + (wc * 64 + fr) * 128;  // + j*2048

    // staging addressing (pre-swizzled global source)
    const int sr  = lane >> 3;
    const int swz = ((lane & 7) ^ sr) * 8;
    const int r0  = wave * 16 + sr;
    const __hip_bfloat16* gA0 = pA    + (size_t)(m0 + r0) * Kd + swz;
    const __hip_bfloat16* gA1 = pB    + (size_t)(m0 + r0) * Kd + swz;
    const __hip_bfloat16* gB0 = prevT + (size_t)(n0 + r0) * Kd + swz;
    const __hip_bfloat16* gB1 = prevT + (size_t)(n0 + 128 + r0) * Kd + swz;

    f32x4 acc[8][4] = {};
    bf16x8 a[8], b[8];

#define STG(GP, BB, HOFF, KT) {                                             \
    char* lb = smem + (BB) + (HOFF) + wave * 2048;                          \
    gload_lds16((GP) + (KT), lb);                                           \
    gload_lds16((GP) + (KT) + 8 * Kd, lb + 1024); }

#define RD_ALO(BB) _Pragma("unroll") for (int i = 0; i < 4; ++i) {          \
    a[i*2]   = *(const bf16x8*)(smem + (BB) + aoffs + i * 2048 + c0);       \
    a[i*2+1] = *(const bf16x8*)(smem + (BB) + aoffs + i * 2048 + c1); }
#define RD_AHI(BB) _Pragma("unroll") for (int i = 0; i < 4; ++i) {          \
    a[i*2]   = *(const bf16x8*)(smem + (BB) + aoffs + 8192 + i * 2048 + c0);\
    a[i*2+1] = *(const bf16x8*)(smem + (BB) + aoffs + 8192 + i * 2048 + c1); }
#define RD_BLO(BB) _Pragma("unroll") for (int j = 0; j < 2; ++j) {          \
    b[j*2]   = *(const bf16x8*)(smem + (BB) + boffs + j * 2048 + c0);       \
    b[j*2+1] = *(const bf16x8*)(smem + (BB) + boffs + j * 2048 + c1); }
#define RD_BHI(BB) _Pragma("unroll") for (int j = 0; j < 2; ++j) {          \
    b[4+j*2]   = *(const bf16x8*)(smem + (BB) + boffs + 4096 + j * 2048 + c0); \
    b[4+j*2+1] = *(const bf16x8*)(smem + (BB) + boffs + 4096 + j * 2048 + c1); }

#define BAR __builtin_amdgcn_s_barrier()
#define VMW(S) asm volatile("s_waitcnt " S ::: "memory")

#define MM(I0, J0, BB0)                                                     \
    asm volatile("s_waitcnt lgkmcnt(0)" ::: "memory");                      \
    __builtin_amdgcn_sched_barrier(0);                                      \
    __builtin_amdgcn_s_setprio(1);                                          \
    _Pragma("unroll") for (int i = 0; i < 4; ++i)                           \
    _Pragma("unroll") for (int j = 0; j < 2; ++j)                           \
    _Pragma("unroll") for (int ks = 0; ks < 2; ++ks)                        \
        acc[(I0)+i][(J0)+j] = __builtin_amdgcn_mfma_f32_16x16x32_bf16(      \
            a[i*2+ks], b[(BB0)+j*2+ks], acc[(I0)+i][(J0)+j], 0, 0, 0);      \
    __builtin_amdgcn_s_setprio(0);

// One K-tile = 4 phases (reads same-phase, 12/4/8/0). Stage calendar (tile T):
//   ph1: gB1(T+1)->NXT   ph2: gA0(T+1)->NXT   ph3: gA1(T+1)->NXT
//   ph4: gB0(T+2)->CUR   then the tile's ONLY vmcnt.
// At T.ph4's vmcnt(2): outstanding (own-wave) = {gB1,gA0,gA1}(T+1) + gB0(T+2)
// = 8 -> confirms everything older incl. gB0(T+1) [staged T-1.ph4] and all of
// tile T+1's halves except the newest 2 -> wait-to-2 confirms gB1/gA0/gA1(T+1)
// whose ages are 3/2/1 phases (1-phase one is L2-hot pA/pB). BAR seals
// cross-wave. WAR: ph4's gB0(T+2)->CUR B-lo region last read at T.ph1 (3
// barrier-pairs prior); ph1-3 stages into NXT last read at T-1.ph3.
#define TILE(T, CURB, NXTB, SG, SG1, VMSTR) {                               \
    RD_ALO(CURB) RD_BLO(CURB)                                               \
    if (SG) STG(gB1, NXTB, 49152, ((T)+1)*64)                               \
    asm volatile("s_waitcnt lgkmcnt(8)" ::: "memory");                      \
    BAR;                                                                    \
    MM(0, 0, 0) BAR;                                                        \
    RD_BHI(CURB)                                                            \
    if (SG) STG(gA0, NXTB, 0, ((T)+1)*64)                                   \
    BAR;                                                                    \
    MM(0, 2, 4) BAR;                                                        \
    RD_AHI(CURB)                                                            \
    if (SG) STG(gA1, NXTB, 16384, ((T)+1)*64)                               \
    BAR;                                                                    \
    MM(4, 2, 4) BAR;                                                        \
    if (SG1) STG(gB0, CURB, 32768, ((T)+2)*64)                              \
    VMW(VMSTR); BAR;                                                        \
    MM(4, 0, 0) BAR;                                                        \
}

    // prologue: tile0 all 4 halves -> buf0, plus gB0(1) -> buf1 (its ph4 slot)
    STG(gB0, 0, 32768, 0)
    STG(gB1, 0, 49152, 0)
    STG(gA0, 0, 0,     0)
    STG(gA1, 0, 16384, 0)
    STG(gB0, 65536, 32768, 64)
    VMW("vmcnt(2)");          // confirm tile0's 8 loads; gB0(1) in flight
    BAR;

    for (int t = 0; t < 14; t += 2) {
        TILE(t,     0,     65536, 1, 1, "vmcnt(2)")
        TILE(t + 1, 65536, 0,     1, 1, "vmcnt(2)")
    }
    TILE(14, 0,     65536, 1, 0, "vmcnt(0)")   // stages rest of 15; confirm all
    TILE(15, 65536, 0,     0, 0, "vmcnt(0)")   // nothing outstanding (free)

#undef TILE
#undef MM
#undef STG
#undef RD_ALO
#undef RD_AHI
#undef RD_BLO
#undef RD_BHI
#undef BAR
#undef VMW

    // ---- epilogue: exchange b-acc via LDS, fuse bilinear coefficients ----
    __syncthreads();
    if (wr == 1) {
        #pragma unroll
        for (int i = 0; i < 8; ++i) {
            #pragma unroll
            for (int j = 0; j < 4; ++j) {
                const int off = ((((wc * 8 + i) * 4 + j) * 64) + lane) * 16;
                *(f32x4*)(smem + off) = acc[i][j];
            }
        }
    }
    __syncthreads();
    if (wr == 0) {
        const int hi = lane >> 4;
        #pragma unroll
        for (int i = 0; i < 8; ++i) {
            float4 cc[4];
            #pragma unroll
            for (int r = 0; r < 4; ++r) cc[r] = coef[m0 + i * 16 + hi * 4 + r];
            #pragma unroll
            for (int j = 0; j < 4; ++j) {
                const f32x4 bb = *(const f32x4*)(smem + ((((wc * 8 + i) * 4 + j) * 64) + lane) * 16);
                const int n = n0 + wc * 64 + j * 16 + fr;
                #pragma unroll
                for (int r = 0; r < 4; ++r) {
                    const int m = m0 + i * 16 + hi * 4 + r;
                    const float aa = acc[i][j][r];
                    out[(size_t)m * Nd + n] = cc[r].x + cc[r].y * aa + cc[r].z * bb[r]
                                            + cc[r].w * (aa * bb[r]);
                }
            }
        }
    }
}

// ---------------------------------------------------------------------------
extern "C" void kernel_launch(void* const* d_in, const int* in_sizes, int n_in,
                              void* d_out, int out_size, void* d_ws, size_t ws_size,
                              hipStream_t stream)
{
    const float* prev = (const float*)d_in[0];   // (prev_size, batch)
    const float* WA   = (const float*)d_in[1];   // (size, prev_size)
    const float* WB   = (const float*)d_in[2];   // (size, prev_size)
    const float* TW   = (const float*)d_in[3];   // (16, size)
    float* out = (float*)d_out;                  // (size, batch)

    const int size      = in_sizes[3] / 16;          // 1024
    const int prev_size = in_sizes[1] / size;        // 1024
    const int batch     = in_sizes[0] / prev_size;   // 16384

    char* ws = (char*)d_ws;
    __hip_bfloat16* prevT = (__hip_bfloat16*)ws;     // 32MB
    size_t off = (size_t)batch * prev_size * sizeof(__hip_bfloat16);
    __hip_bfloat16* pA = (__hip_bfloat16*)(ws + off);
    off += (size_t)size * prev_size * sizeof(__hip_bfloat16);
    __hip_bfloat16* pB = (__hip_bfloat16*)(ws + off);
    off += (size_t)size * prev_size * sizeof(__hip_bfloat16);
    float4* coef = (float4*)(ws + off);

    softmax_rows_bf16<<<dim3(2 * size), dim3(256), 0, stream>>>(
        WA, WB, pA, pB, size, prev_size);
    table_coef<<<dim3((size + 255) / 256), dim3(256), 0, stream>>>(TW, coef, size);
    transpose_bf16<<<dim3(batch / 64, prev_size / 64), dim3(256), 0, stream>>>(
        prev, prevT, prev_size, batch);
    dual_gemm8<<<dim3(batch / 256, size / 128), dim3(512), 0, stream>>>(
        pA, pB, prevT, coef, out);
}